// Round 1
// baseline (1803.124 us; speedup 1.0000x reference)
//
#include <hip/hip_runtime.h>

// NetEdge GNN: 2x (edge-aggr concat -> scatter-add propagate -> rel/root MLP),
// then global_add_pool + final MLP. All fp32.

namespace {
constexpr int N  = 50000;    // nodes
constexpr int E  = 1600000;  // edges
constexpr int G  = 256;      // graphs
constexpr int EC = 32;       // edge channels
constexpr int H  = 64;       // hidden / node channels
constexpr int D  = 96;       // concat dim (64 + 32)
constexpr int OUTC = 10;     // classes
}

// ---- edge_aggr[row[e]] += edge_attr[e]  (E x 32) ----
__global__ void k_edge_aggr(const float* __restrict__ edge_attr,
                            const int* __restrict__ row,
                            float* __restrict__ edge_aggr) {
    int tid = blockIdx.x * blockDim.x + threadIdx.x;
    if (tid >= E * EC) return;
    int e = tid >> 5;          // /32
    int c = tid & 31;
    atomicAdd(&edge_aggr[row[e] * EC + c], edge_attr[tid]);
}

// ---- xc[:, 0:64] = x ----
__global__ void k_copy_x(const float* __restrict__ x, float* __restrict__ xc) {
    int tid = blockIdx.x * blockDim.x + threadIdx.x;
    if (tid >= N * H) return;
    int n = tid >> 6;
    int j = tid & 63;
    xc[n * D + j] = x[tid];
}

// ---- xc[:, 64:96] = edge_aggr ----
__global__ void k_copy_ea(const float* __restrict__ ea, float* __restrict__ xc) {
    int tid = blockIdx.x * blockDim.x + threadIdx.x;
    if (tid >= N * EC) return;
    int n = tid >> 5;
    int c = tid & 31;
    xc[n * D + H + c] = ea[tid];
}

// ---- agg[col[e]] += xc[row[e]]  (one wave per edge, 96 channels) ----
__global__ __launch_bounds__(256) void k_scatter(const float* __restrict__ xc,
                          const int* __restrict__ row,
                          const int* __restrict__ col,
                          float* __restrict__ agg) {
    int wave = blockIdx.x * 4 + (threadIdx.x >> 6);
    int lane = threadIdx.x & 63;
    if (wave >= E) return;
    int r = row[wave];
    int t = col[wave];
    const float* src = xc + (size_t)r * D;
    float*       dst = agg + (size_t)t * D;
    atomicAdd(&dst[lane], src[lane]);
    if (lane < 32) atomicAdd(&dst[H + lane], src[H + lane]);
}

// ---- h_rel = relu(agg @ relW1 + relb1); h_root = relu(xc @ rootW1 + rootb1) ----
// wave per node, lane = output channel; weights staged in LDS.
__global__ __launch_bounds__(256) void k_mlp1(const float* __restrict__ agg,
                       const float* __restrict__ xc,
                       const float* __restrict__ relW1, const float* __restrict__ relb1,
                       const float* __restrict__ rootW1, const float* __restrict__ rootb1,
                       float* __restrict__ hrel, float* __restrict__ hroot) {
    __shared__ float sWr[D * H];
    __shared__ float sWo[D * H];
    for (int i = threadIdx.x; i < D * H; i += 256) {
        sWr[i] = relW1[i];
        sWo[i] = rootW1[i];
    }
    __syncthreads();
    int lane = threadIdx.x & 63;
    int wid  = threadIdx.x >> 6;
    int nwaves = gridDim.x * 4;
    float br = relb1[lane];
    float bo = rootb1[lane];
    for (int n = blockIdx.x * 4 + wid; n < N; n += nwaves) {
        const float* a = agg + (size_t)n * D;
        const float* xr = xc + (size_t)n * D;
        float accr = br, acco = bo;
        #pragma unroll 8
        for (int k = 0; k < D; ++k) {
            float av = a[k];
            float xv = xr[k];
            accr += av * sWr[k * H + lane];
            acco += xv * sWo[k * H + lane];
        }
        hrel[(size_t)n * H + lane]  = fmaxf(accr, 0.f);
        hroot[(size_t)n * H + lane] = fmaxf(acco, 0.f);
    }
}

// ---- x_out = relu(hrel @ relW2 + relb2 + hroot @ rootW2 + rootb2) ----
__global__ __launch_bounds__(256) void k_mlp2(const float* __restrict__ hrel,
                       const float* __restrict__ hroot,
                       const float* __restrict__ relW2, const float* __restrict__ relb2,
                       const float* __restrict__ rootW2, const float* __restrict__ rootb2,
                       float* __restrict__ xout) {
    __shared__ float sWr[H * H];
    __shared__ float sWo[H * H];
    for (int i = threadIdx.x; i < H * H; i += 256) {
        sWr[i] = relW2[i];
        sWo[i] = rootW2[i];
    }
    __syncthreads();
    int lane = threadIdx.x & 63;
    int wid  = threadIdx.x >> 6;
    int nwaves = gridDim.x * 4;
    float b = relb2[lane] + rootb2[lane];
    for (int n = blockIdx.x * 4 + wid; n < N; n += nwaves) {
        const float* hr = hrel + (size_t)n * H;
        const float* ho = hroot + (size_t)n * H;
        float acc = b;
        #pragma unroll 8
        for (int k = 0; k < H; ++k) {
            acc += hr[k] * sWr[k * H + lane] + ho[k] * sWo[k * H + lane];
        }
        xout[(size_t)n * H + lane] = fmaxf(acc, 0.f);
    }
}

// ---- pooled[batch[n]] += x[n] ----
__global__ void k_pool(const float* __restrict__ x, const int* __restrict__ batch,
                       float* __restrict__ pooled) {
    int tid = blockIdx.x * blockDim.x + threadIdx.x;
    if (tid >= N * H) return;
    int n = tid >> 6;
    int j = tid & 63;
    atomicAdd(&pooled[batch[n] * H + j], x[tid]);
}

// ---- out = relu(pooled @ finW1 + finb1) @ finW2 + finb2 ----
__global__ void k_final(const float* __restrict__ pooled,
                        const float* __restrict__ W1, const float* __restrict__ b1,
                        const float* __restrict__ W2, const float* __restrict__ b2,
                        float* __restrict__ out) {
    __shared__ float h[H];
    int g = blockIdx.x;
    int j = threadIdx.x;
    const float* p = pooled + (size_t)g * H;
    float acc = b1[j];
    #pragma unroll 8
    for (int k = 0; k < H; ++k) acc += p[k] * W1[k * H + j];
    h[j] = fmaxf(acc, 0.f);
    __syncthreads();
    if (j < OUTC) {
        float o = b2[j];
        #pragma unroll 8
        for (int k = 0; k < H; ++k) o += h[k] * W2[k * OUTC + j];
        out[(size_t)g * OUTC + j] = o;
    }
}

extern "C" void kernel_launch(void* const* d_in, const int* in_sizes, int n_in,
                              void* d_out, int out_size, void* d_ws, size_t ws_size,
                              hipStream_t stream) {
    const float* x         = (const float*)d_in[0];
    const float* edge_attr = (const float*)d_in[1];
    // per-layer params: [l*8 + 0..3] = rel (W1,b1,W2,b2); [l*8 + 4..7] = root
    const float* P[16];
    for (int i = 0; i < 16; ++i) P[i] = (const float*)d_in[2 + i];
    const float* finW1 = (const float*)d_in[18];
    const float* finb1 = (const float*)d_in[19];
    const float* finW2 = (const float*)d_in[20];
    const float* finb2 = (const float*)d_in[21];
    const int* row   = (const int*)d_in[22];
    const int* col   = row + E;
    const int* batch = (const int*)d_in[23];
    float* out = (float*)d_out;

    float* ws = (float*)d_ws;
    float* edge_aggr = ws;  ws += (size_t)N * EC;   // 1.6M floats
    float* xc        = ws;  ws += (size_t)N * D;    // 4.8M
    float* agg       = ws;  ws += (size_t)N * D;    // 4.8M
    float* hrel      = ws;  ws += (size_t)N * H;    // 3.2M
    float* hroot     = ws;  ws += (size_t)N * H;    // 3.2M
    float* xbuf      = ws;  ws += (size_t)N * H;    // 3.2M
    float* pooled    = ws;  ws += (size_t)G * H;    // 16K
    (void)ws_size; (void)n_in; (void)in_sizes; (void)out_size;

    // edge_aggr (same for both layers)
    hipMemsetAsync(edge_aggr, 0, (size_t)N * EC * sizeof(float), stream);
    k_edge_aggr<<<(E * EC + 255) / 256, 256, 0, stream>>>(edge_attr, row, edge_aggr);

    const float* xin = x;
    for (int l = 0; l < 2; ++l) {
        const float* relW1  = P[l * 8 + 0];
        const float* relb1  = P[l * 8 + 1];
        const float* relW2  = P[l * 8 + 2];
        const float* relb2  = P[l * 8 + 3];
        const float* rootW1 = P[l * 8 + 4];
        const float* rootb1 = P[l * 8 + 5];
        const float* rootW2 = P[l * 8 + 6];
        const float* rootb2 = P[l * 8 + 7];

        k_copy_x<<<(N * H + 255) / 256, 256, 0, stream>>>(xin, xc);
        k_copy_ea<<<(N * EC + 255) / 256, 256, 0, stream>>>(edge_aggr, xc);
        hipMemsetAsync(agg, 0, (size_t)N * D * sizeof(float), stream);
        k_scatter<<<(E + 3) / 4, 256, 0, stream>>>(xc, row, col, agg);
        k_mlp1<<<1024, 256, 0, stream>>>(agg, xc, relW1, relb1, rootW1, rootb1, hrel, hroot);
        k_mlp2<<<1024, 256, 0, stream>>>(hrel, hroot, relW2, relb2, rootW2, rootb2, xbuf);
        xin = xbuf;
    }

    hipMemsetAsync(pooled, 0, (size_t)G * H * sizeof(float), stream);
    k_pool<<<(N * H + 255) / 256, 256, 0, stream>>>(xbuf, batch, pooled);
    k_final<<<G, 64, 0, stream>>>(pooled, finW1, finb1, finW2, finb2, out);
}

// Round 2
// 1572.616 us; speedup vs baseline: 1.1466x; 1.1466x over previous
//
#include <hip/hip_runtime.h>

// NetEdge GNN, gather formulation:
//   build CSR(by row=source) + CSC(by col=target) on device each launch,
//   then: edge_aggr = gather-sum(edge_attr)   [CSR]
//         agg       = gather-sum(xc[src])     [CSC]  (replaces atomic scatter)
//   MLPs: wave-per-node with weights staged in LDS. Pool: register pre-reduce.

namespace {
constexpr int N  = 50000;    // nodes
constexpr int E  = 1600000;  // edges
constexpr int G  = 256;      // graphs
constexpr int EC = 32;       // edge channels
constexpr int H  = 64;       // hidden / node channels
constexpr int D  = 96;       // concat dim (64 + 32)
constexpr int OUTC = 10;     // classes
}

// ---- degree histograms for both orderings ----
__global__ void k_hist(const int* __restrict__ row, const int* __restrict__ col,
                       int* __restrict__ degR, int* __restrict__ degC) {
    int e = blockIdx.x * 256 + threadIdx.x;
    if (e >= E) return;
    atomicAdd(&degR[row[e]], 1);
    atomicAdd(&degC[col[e]], 1);
}

// ---- exclusive scan over N degrees, one workgroup of 1024 threads ----
__global__ __launch_bounds__(1024) void k_scan(const int* __restrict__ deg,
                                               int* __restrict__ off,
                                               int* __restrict__ curs) {
    __shared__ int sums[1024];
    int tid = threadIdx.x;
    const int CH = (N + 1023) / 1024;  // 49
    int base = tid * CH;
    int s = 0;
    for (int i = 0; i < CH; ++i) {
        int idx = base + i;
        if (idx < N) s += deg[idx];
    }
    sums[tid] = s;
    __syncthreads();
    for (int d = 1; d < 1024; d <<= 1) {
        int v = sums[tid];
        int u = (tid >= d) ? sums[tid - d] : 0;
        __syncthreads();
        sums[tid] = v + u;
        __syncthreads();
    }
    int run = (tid == 0) ? 0 : sums[tid - 1];
    for (int i = 0; i < CH; ++i) {
        int idx = base + i;
        if (idx < N) {
            off[idx] = run;
            curs[idx] = run;
            run += deg[idx];
        }
    }
    if (tid == 1023) off[N] = run;
}

// ---- bucket edges: CSR stores edge id, CSC stores source node ----
__global__ void k_bucket(const int* __restrict__ row, const int* __restrict__ col,
                         int* __restrict__ cursR, int* __restrict__ cursC,
                         int* __restrict__ eid, int* __restrict__ srcrow) {
    int e = blockIdx.x * 256 + threadIdx.x;
    if (e >= E) return;
    int r = row[e], c = col[e];
    int q = atomicAdd(&cursR[r], 1);
    eid[q] = e;
    int p = atomicAdd(&cursC[c], 1);
    srcrow[p] = r;
}

// ---- edge_aggr gather; writes straight into xc1/xc2 tails ----
__global__ __launch_bounds__(256) void k_ea_gather(const float* __restrict__ edge_attr,
                                                   const int* __restrict__ eid,
                                                   const int* __restrict__ offR,
                                                   float* __restrict__ xc1,
                                                   float* __restrict__ xc2) {
    int n = blockIdx.x * 8 + (threadIdx.x >> 5);   // 8 nodes per block, 32 lanes each
    int c = threadIdx.x & 31;
    if (n >= N) return;
    int b = offR[n], e_end = offR[n + 1];
    float s = 0.f;
    for (int i = b; i < e_end; ++i) {
        int e = eid[i];  // same addr across 32 lanes -> broadcast
        s += edge_attr[(size_t)e * EC + c];
    }
    xc1[(size_t)n * D + H + c] = s;
    xc2[(size_t)n * D + H + c] = s;
}

// ---- xc1[:, 0:64] = x ----
__global__ void k_fill_x(const float* __restrict__ x, float* __restrict__ xc1) {
    int tid = blockIdx.x * 256 + threadIdx.x;
    if (tid >= N * H) return;
    xc1[(size_t)(tid >> 6) * D + (tid & 63)] = x[tid];
}

// ---- agg[n] = sum over incoming edges of xc[src]  (wave per node, gather) ----
__global__ __launch_bounds__(256) void k_gprop(const float* __restrict__ xc,
                                               const int* __restrict__ srcrow,
                                               const int* __restrict__ offC,
                                               float* __restrict__ agg) {
    int n = blockIdx.x * 4 + (threadIdx.x >> 6);
    int lane = threadIdx.x & 63;
    if (n >= N) return;
    int b = offC[n], e_end = offC[n + 1];
    float a0 = 0.f, a1 = 0.f;
    for (int i0 = b; i0 < e_end; i0 += 64) {
        int cnt = min(64, e_end - i0);
        int r = (lane < cnt) ? srcrow[i0 + lane] : 0;
        int j = 0;
        for (; j + 1 < cnt; j += 2) {
            int r0 = __shfl(r, j);
            int r1 = __shfl(r, j + 1);
            const float* s0 = xc + (size_t)r0 * D;
            const float* s1 = xc + (size_t)r1 * D;
            float v0 = s0[lane], v1 = s1[lane];
            float w0 = 0.f, w1 = 0.f;
            if (lane < 32) { w0 = s0[H + lane]; w1 = s1[H + lane]; }
            a0 += v0 + v1;
            a1 += w0 + w1;
        }
        if (j < cnt) {
            int r0 = __shfl(r, j);
            const float* s0 = xc + (size_t)r0 * D;
            a0 += s0[lane];
            if (lane < 32) a1 += s0[H + lane];
        }
    }
    agg[(size_t)n * D + lane] = a0;
    if (lane < 32) agg[(size_t)n * D + H + lane] = a1;
}

// ---- h_rel = relu(agg @ relW1 + b); h_root = relu(xc @ rootW1 + b) ----
__global__ __launch_bounds__(256) void k_mlp1(const float* __restrict__ agg,
                       const float* __restrict__ xc,
                       const float* __restrict__ relW1, const float* __restrict__ relb1,
                       const float* __restrict__ rootW1, const float* __restrict__ rootb1,
                       float* __restrict__ hrel, float* __restrict__ hroot) {
    __shared__ float sWr[D * H];
    __shared__ float sWo[D * H];
    for (int i = threadIdx.x; i < D * H; i += 256) {
        sWr[i] = relW1[i];
        sWo[i] = rootW1[i];
    }
    __syncthreads();
    int lane = threadIdx.x & 63;
    int wid  = threadIdx.x >> 6;
    int nwaves = gridDim.x * 4;
    float br = relb1[lane];
    float bo = rootb1[lane];
    for (int n = blockIdx.x * 4 + wid; n < N; n += nwaves) {
        const float* a  = agg + (size_t)n * D;
        const float* xr = xc  + (size_t)n * D;
        float accr = br, acco = bo;
        #pragma unroll 8
        for (int k = 0; k < D; ++k) {
            accr += a[k]  * sWr[k * H + lane];
            acco += xr[k] * sWo[k * H + lane];
        }
        hrel[(size_t)n * H + lane]  = fmaxf(accr, 0.f);
        hroot[(size_t)n * H + lane] = fmaxf(acco, 0.f);
    }
}

// ---- x_out = relu(hrel @ relW2 + hroot @ rootW2 + b), strided output ----
__global__ __launch_bounds__(256) void k_mlp2(const float* __restrict__ hrel,
                       const float* __restrict__ hroot,
                       const float* __restrict__ relW2, const float* __restrict__ relb2,
                       const float* __restrict__ rootW2, const float* __restrict__ rootb2,
                       float* __restrict__ xout, int ostride) {
    __shared__ float sWr[H * H];
    __shared__ float sWo[H * H];
    for (int i = threadIdx.x; i < H * H; i += 256) {
        sWr[i] = relW2[i];
        sWo[i] = rootW2[i];
    }
    __syncthreads();
    int lane = threadIdx.x & 63;
    int wid  = threadIdx.x >> 6;
    int nwaves = gridDim.x * 4;
    float b = relb2[lane] + rootb2[lane];
    for (int n = blockIdx.x * 4 + wid; n < N; n += nwaves) {
        const float* hr = hrel  + (size_t)n * H;
        const float* ho = hroot + (size_t)n * H;
        float acc = b;
        #pragma unroll 8
        for (int k = 0; k < H; ++k) {
            acc += hr[k] * sWr[k * H + lane] + ho[k] * sWo[k * H + lane];
        }
        xout[(size_t)n * ostride + lane] = fmaxf(acc, 0.f);
    }
}

// ---- pooled[batch[n]] += x[n], 16-node register pre-reduce (batch is sorted) ----
__global__ __launch_bounds__(256) void k_pool(const float* __restrict__ x,
                                              const int* __restrict__ batch,
                                              float* __restrict__ pooled) {
    int c = threadIdx.x & 63;
    int grp = blockIdx.x * 4 + (threadIdx.x >> 6);
    int n0 = grp * 16;
    if (n0 >= N) return;
    int nend = min(n0 + 16, N);
    int curb = batch[n0];
    float acc = 0.f;
    for (int n = n0; n < nend; ++n) {
        int b = batch[n];
        if (b != curb) {
            atomicAdd(&pooled[curb * H + c], acc);
            acc = 0.f;
            curb = b;
        }
        acc += x[(size_t)n * H + c];
    }
    atomicAdd(&pooled[curb * H + c], acc);
}

// ---- out = relu(pooled @ finW1 + finb1) @ finW2 + finb2 ----
__global__ void k_final(const float* __restrict__ pooled,
                        const float* __restrict__ W1, const float* __restrict__ b1,
                        const float* __restrict__ W2, const float* __restrict__ b2,
                        float* __restrict__ out) {
    __shared__ float h[H];
    int g = blockIdx.x;
    int j = threadIdx.x;
    const float* p = pooled + (size_t)g * H;
    float acc = b1[j];
    #pragma unroll 8
    for (int k = 0; k < H; ++k) acc += p[k] * W1[k * H + j];
    h[j] = fmaxf(acc, 0.f);
    __syncthreads();
    if (j < OUTC) {
        float o = b2[j];
        #pragma unroll 8
        for (int k = 0; k < H; ++k) o += h[k] * W2[k * OUTC + j];
        out[(size_t)g * OUTC + j] = o;
    }
}

extern "C" void kernel_launch(void* const* d_in, const int* in_sizes, int n_in,
                              void* d_out, int out_size, void* d_ws, size_t ws_size,
                              hipStream_t stream) {
    const float* x         = (const float*)d_in[0];
    const float* edge_attr = (const float*)d_in[1];
    const float* P[16];
    for (int i = 0; i < 16; ++i) P[i] = (const float*)d_in[2 + i];
    const float* finW1 = (const float*)d_in[18];
    const float* finb1 = (const float*)d_in[19];
    const float* finW2 = (const float*)d_in[20];
    const float* finb2 = (const float*)d_in[21];
    const int* row   = (const int*)d_in[22];
    const int* col   = row + E;
    const int* batch = (const int*)d_in[23];
    float* out = (float*)d_out;
    (void)ws_size; (void)n_in; (void)in_sizes; (void)out_size;

    // workspace layout
    float* fw = (float*)d_ws;
    float* xc1    = fw;  fw += (size_t)N * D;   // 4.8M
    float* xc2    = fw;  fw += (size_t)N * D;   // 4.8M
    float* agg    = fw;  fw += (size_t)N * D;   // 4.8M (layer-2 mlp2 output reuses head)
    float* hrel   = fw;  fw += (size_t)N * H;   // 3.2M
    float* hroot  = fw;  fw += (size_t)N * H;   // 3.2M
    float* pooled = fw;  fw += (size_t)G * H;
    int* iw = (int*)fw;
    int* degR   = iw;  iw += N;
    int* degC   = iw;  iw += N;
    int* offR   = iw;  iw += N + 1;
    int* offC   = iw;  iw += N + 1;
    int* cursR  = iw;  iw += N;
    int* cursC  = iw;  iw += N;
    int* eid    = iw;  iw += E;
    int* srcrow = iw;  iw += E;

    // --- build CSR/CSC ---
    hipMemsetAsync(degR, 0, 2 * (size_t)N * sizeof(int), stream);  // degR+degC adjacent
    hipMemsetAsync(pooled, 0, (size_t)G * H * sizeof(float), stream);
    k_hist<<<(E + 255) / 256, 256, 0, stream>>>(row, col, degR, degC);
    k_scan<<<1, 1024, 0, stream>>>(degR, offR, cursR);
    k_scan<<<1, 1024, 0, stream>>>(degC, offC, cursC);
    k_bucket<<<(E + 255) / 256, 256, 0, stream>>>(row, col, cursR, cursC, eid, srcrow);

    // --- edge_aggr into xc tails; x into xc1 head ---
    k_ea_gather<<<(N + 7) / 8, 256, 0, stream>>>(edge_attr, eid, offR, xc1, xc2);
    k_fill_x<<<(N * H + 255) / 256, 256, 0, stream>>>(x, xc1);

    // --- layer 1 ---
    k_gprop<<<(N + 3) / 4, 256, 0, stream>>>(xc1, srcrow, offC, agg);
    k_mlp1<<<1024, 256, 0, stream>>>(agg, xc1, P[0], P[1], P[4], P[5], hrel, hroot);
    k_mlp2<<<1024, 256, 0, stream>>>(hrel, hroot, P[2], P[3], P[6], P[7], xc2, D);

    // --- layer 2 ---
    k_gprop<<<(N + 3) / 4, 256, 0, stream>>>(xc2, srcrow, offC, agg);
    k_mlp1<<<1024, 256, 0, stream>>>(agg, xc2, P[8], P[9], P[12], P[13], hrel, hroot);
    k_mlp2<<<1024, 256, 0, stream>>>(hrel, hroot, P[10], P[11], P[14], P[15], agg, H);

    // --- pool + head ---
    k_pool<<<(N / 16 + 3) / 4, 256, 0, stream>>>(agg, batch, pooled);
    k_final<<<G, 64, 0, stream>>>(pooled, finW1, finb1, finW2, finb2, out);
}

// Round 3
// 1025.102 us; speedup vs baseline: 1.7590x; 1.5341x over previous
//
#include <hip/hip_runtime.h>

// NetEdge GNN, gather formulation with two-level MSD-binned CSR/CSC build.
//   Round-2 lesson: single-shot atomic bucketing wrote 194 MB (16x ampl.,
//   cross-XCD line ping-pong). Now: coarse-bin (196 buckets, coalesced packed
//   stores) then per-bucket fine bin (one block per bucket, LDS hist+scan,
//   writes confined to a 32 KB window, zero global atomics).

namespace {
constexpr int N  = 50000;    // nodes
constexpr int E  = 1600000;  // edges
constexpr int G  = 256;      // graphs
constexpr int EC = 32;       // edge channels
constexpr int H  = 64;       // hidden / node channels
constexpr int D  = 96;       // concat dim (64 + 32)
constexpr int OUTC = 10;     // classes
constexpr int NB = (N + 255) / 256;   // 196 coarse buckets (node >> 8)
constexpr int CHUNK = 4096;           // edges per pass-1 block
}

// ---- pass 1a: coarse histograms (LDS-staged, 1 global atomic per bin/block) ----
__global__ __launch_bounds__(256) void k_p1hist(const int* __restrict__ row,
                                                const int* __restrict__ col,
                                                int* __restrict__ cntR,
                                                int* __restrict__ cntC) {
    __shared__ int hR[NB], hC[NB];
    for (int i = threadIdx.x; i < NB; i += 256) { hR[i] = 0; hC[i] = 0; }
    __syncthreads();
    int base = blockIdx.x * CHUNK;
    int end = min(base + CHUNK, E);
    for (int e = base + threadIdx.x; e < end; e += 256) {
        atomicAdd(&hR[row[e] >> 8], 1);
        atomicAdd(&hC[col[e] >> 8], 1);
    }
    __syncthreads();
    for (int i = threadIdx.x; i < NB; i += 256) {
        if (hR[i]) atomicAdd(&cntR[i], hR[i]);
        if (hC[i]) atomicAdd(&cntC[i], hC[i]);
    }
}

// ---- pass 1b: scan 196 bucket counts -> bases + cursors; off[N]=E ----
__global__ __launch_bounds__(256) void k_bscan(const int* __restrict__ cntR,
                                               const int* __restrict__ cntC,
                                               int* __restrict__ baseR, int* __restrict__ baseC,
                                               int* __restrict__ curR,  int* __restrict__ curC,
                                               int* __restrict__ offR,  int* __restrict__ offC) {
    __shared__ int sR[256], sC[256];
    int t = threadIdx.x;
    sR[t] = (t < NB) ? cntR[t] : 0;
    sC[t] = (t < NB) ? cntC[t] : 0;
    __syncthreads();
    for (int d = 1; d < 256; d <<= 1) {
        int vR = sR[t], vC = sC[t];
        int uR = (t >= d) ? sR[t - d] : 0;
        int uC = (t >= d) ? sC[t - d] : 0;
        __syncthreads();
        sR[t] = vR + uR; sC[t] = vC + uC;
        __syncthreads();
    }
    if (t < NB) {
        int bR = (t == 0) ? 0 : sR[t - 1];
        int bC = (t == 0) ? 0 : sC[t - 1];
        baseR[t] = bR; curR[t] = bR;
        baseC[t] = bC; curC[t] = bC;
    }
    if (t == 0) { offR[N] = E; offC[N] = E; }
}

// ---- pass 1c: coarse scatter of packed (key<<32|val), runs of ~21/bin ----
__global__ __launch_bounds__(256) void k_p1scat(const int* __restrict__ row,
                                                const int* __restrict__ col,
                                                int* __restrict__ curR, int* __restrict__ curC,
                                                unsigned long long* __restrict__ kvR,
                                                unsigned long long* __restrict__ kvC) {
    __shared__ int hR[NB], hC[NB];
    __shared__ int cR[NB], cC[NB];
    for (int i = threadIdx.x; i < NB; i += 256) { hR[i] = 0; hC[i] = 0; }
    __syncthreads();
    int base = blockIdx.x * CHUNK;
    int end = min(base + CHUNK, E);
    for (int e = base + threadIdx.x; e < end; e += 256) {
        atomicAdd(&hR[row[e] >> 8], 1);
        atomicAdd(&hC[col[e] >> 8], 1);
    }
    __syncthreads();
    for (int i = threadIdx.x; i < NB; i += 256) {
        cR[i] = hR[i] ? atomicAdd(&curR[i], hR[i]) : 0;
        cC[i] = hC[i] ? atomicAdd(&curC[i], hC[i]) : 0;
    }
    __syncthreads();
    for (int e = base + threadIdx.x; e < end; e += 256) {
        int r = row[e], c = col[e];
        int pR = atomicAdd(&cR[r >> 8], 1);
        kvR[pR] = ((unsigned long long)(unsigned)r << 32) | (unsigned)e;
        int pC = atomicAdd(&cC[c >> 8], 1);
        kvC[pC] = ((unsigned long long)(unsigned)c << 32) | (unsigned)r;
    }
}

// ---- pass 2: per-bucket fine bin; block b<NB handles CSR, else CSC ----
__global__ __launch_bounds__(256) void k_p2(const unsigned long long* __restrict__ kvR,
                                            const unsigned long long* __restrict__ kvC,
                                            const int* __restrict__ baseR, const int* __restrict__ baseC,
                                            const int* __restrict__ cntR,  const int* __restrict__ cntC,
                                            int* __restrict__ offR, int* __restrict__ offC,
                                            int* __restrict__ eid, int* __restrict__ srcrow) {
    bool isC = blockIdx.x >= NB;
    int b = isC ? blockIdx.x - NB : blockIdx.x;
    const unsigned long long* kv = isC ? kvC : kvR;
    int sbase = isC ? baseC[b] : baseR[b];
    int scnt  = isC ? cntC[b]  : cntR[b];
    int* off  = isC ? offC : offR;
    int* outv = isC ? srcrow : eid;

    __shared__ int hist[256], s[256], cur[256];
    int t = threadIdx.x;
    hist[t] = 0;
    __syncthreads();
    for (int i = sbase + t; i < sbase + scnt; i += 256) {
        atomicAdd(&hist[(int)(kv[i] >> 32) & 255], 1);
    }
    __syncthreads();
    s[t] = hist[t];
    __syncthreads();
    for (int d = 1; d < 256; d <<= 1) {
        int v = s[t];
        int u = (t >= d) ? s[t - d] : 0;
        __syncthreads();
        s[t] = v + u;
        __syncthreads();
    }
    int excl = (t == 0) ? 0 : s[t - 1];
    cur[t] = sbase + excl;
    int node = (b << 8) + t;
    if (node < N) off[node] = sbase + excl;
    __syncthreads();
    for (int i = sbase + t; i < sbase + scnt; i += 256) {
        unsigned long long p = kv[i];
        int lk = (int)(p >> 32) & 255;
        int pos = atomicAdd(&cur[lk], 1);
        outv[pos] = (int)(p & 0xffffffffu);
    }
}

// ---- edge_aggr gather; writes straight into xc1/xc2 tails ----
__global__ __launch_bounds__(256) void k_ea_gather(const float* __restrict__ edge_attr,
                                                   const int* __restrict__ eid,
                                                   const int* __restrict__ offR,
                                                   float* __restrict__ xc1,
                                                   float* __restrict__ xc2) {
    int n = blockIdx.x * 8 + (threadIdx.x >> 5);
    int c = threadIdx.x & 31;
    if (n >= N) return;
    int b = offR[n], e_end = offR[n + 1];
    float s = 0.f;
    for (int i = b; i < e_end; ++i) {
        int e = eid[i];  // broadcast across 32 lanes
        s += edge_attr[(size_t)e * EC + c];
    }
    xc1[(size_t)n * D + H + c] = s;
    xc2[(size_t)n * D + H + c] = s;
}

// ---- xc1[:, 0:64] = x ----
__global__ void k_fill_x(const float* __restrict__ x, float* __restrict__ xc1) {
    int tid = blockIdx.x * 256 + threadIdx.x;
    if (tid >= N * H) return;
    xc1[(size_t)(tid >> 6) * D + (tid & 63)] = x[tid];
}

// ---- agg[n] = sum over incoming edges of xc[src]  (wave per node, gather) ----
__global__ __launch_bounds__(256) void k_gprop(const float* __restrict__ xc,
                                               const int* __restrict__ srcrow,
                                               const int* __restrict__ offC,
                                               float* __restrict__ agg) {
    int n = blockIdx.x * 4 + (threadIdx.x >> 6);
    int lane = threadIdx.x & 63;
    if (n >= N) return;
    int b = offC[n], e_end = offC[n + 1];
    float a0 = 0.f, a1 = 0.f;
    for (int i0 = b; i0 < e_end; i0 += 64) {
        int cnt = min(64, e_end - i0);
        int r = (lane < cnt) ? srcrow[i0 + lane] : 0;
        int j = 0;
        for (; j + 1 < cnt; j += 2) {
            int r0 = __shfl(r, j);
            int r1 = __shfl(r, j + 1);
            const float* s0 = xc + (size_t)r0 * D;
            const float* s1 = xc + (size_t)r1 * D;
            float v0 = s0[lane], v1 = s1[lane];
            float w0 = 0.f, w1 = 0.f;
            if (lane < 32) { w0 = s0[H + lane]; w1 = s1[H + lane]; }
            a0 += v0 + v1;
            a1 += w0 + w1;
        }
        if (j < cnt) {
            int r0 = __shfl(r, j);
            const float* s0 = xc + (size_t)r0 * D;
            a0 += s0[lane];
            if (lane < 32) a1 += s0[H + lane];
        }
    }
    agg[(size_t)n * D + lane] = a0;
    if (lane < 32) agg[(size_t)n * D + H + lane] = a1;
}

// ---- h_rel = relu(agg @ relW1 + b); h_root = relu(xc @ rootW1 + b) ----
__global__ __launch_bounds__(256) void k_mlp1(const float* __restrict__ agg,
                       const float* __restrict__ xc,
                       const float* __restrict__ relW1, const float* __restrict__ relb1,
                       const float* __restrict__ rootW1, const float* __restrict__ rootb1,
                       float* __restrict__ hrel, float* __restrict__ hroot) {
    __shared__ float sWr[D * H];
    __shared__ float sWo[D * H];
    for (int i = threadIdx.x; i < D * H; i += 256) {
        sWr[i] = relW1[i];
        sWo[i] = rootW1[i];
    }
    __syncthreads();
    int lane = threadIdx.x & 63;
    int wid  = threadIdx.x >> 6;
    int nwaves = gridDim.x * 4;
    float br = relb1[lane];
    float bo = rootb1[lane];
    for (int n = blockIdx.x * 4 + wid; n < N; n += nwaves) {
        const float* a  = agg + (size_t)n * D;
        const float* xr = xc  + (size_t)n * D;
        float accr = br, acco = bo;
        #pragma unroll 8
        for (int k = 0; k < D; ++k) {
            accr += a[k]  * sWr[k * H + lane];
            acco += xr[k] * sWo[k * H + lane];
        }
        hrel[(size_t)n * H + lane]  = fmaxf(accr, 0.f);
        hroot[(size_t)n * H + lane] = fmaxf(acco, 0.f);
    }
}

// ---- x_out = relu(hrel @ relW2 + hroot @ rootW2 + b), strided output ----
__global__ __launch_bounds__(256) void k_mlp2(const float* __restrict__ hrel,
                       const float* __restrict__ hroot,
                       const float* __restrict__ relW2, const float* __restrict__ relb2,
                       const float* __restrict__ rootW2, const float* __restrict__ rootb2,
                       float* __restrict__ xout, int ostride) {
    __shared__ float sWr[H * H];
    __shared__ float sWo[H * H];
    for (int i = threadIdx.x; i < H * H; i += 256) {
        sWr[i] = relW2[i];
        sWo[i] = rootW2[i];
    }
    __syncthreads();
    int lane = threadIdx.x & 63;
    int wid  = threadIdx.x >> 6;
    int nwaves = gridDim.x * 4;
    float b = relb2[lane] + rootb2[lane];
    for (int n = blockIdx.x * 4 + wid; n < N; n += nwaves) {
        const float* hr = hrel  + (size_t)n * H;
        const float* ho = hroot + (size_t)n * H;
        float acc = b;
        #pragma unroll 8
        for (int k = 0; k < H; ++k) {
            acc += hr[k] * sWr[k * H + lane] + ho[k] * sWo[k * H + lane];
        }
        xout[(size_t)n * ostride + lane] = fmaxf(acc, 0.f);
    }
}

// ---- pooled[batch[n]] += x[n], 16-node register pre-reduce (batch sorted) ----
__global__ __launch_bounds__(256) void k_pool(const float* __restrict__ x,
                                              const int* __restrict__ batch,
                                              float* __restrict__ pooled) {
    int c = threadIdx.x & 63;
    int grp = blockIdx.x * 4 + (threadIdx.x >> 6);
    int n0 = grp * 16;
    if (n0 >= N) return;
    int nend = min(n0 + 16, N);
    int curb = batch[n0];
    float acc = 0.f;
    for (int n = n0; n < nend; ++n) {
        int b = batch[n];
        if (b != curb) {
            atomicAdd(&pooled[curb * H + c], acc);
            acc = 0.f;
            curb = b;
        }
        acc += x[(size_t)n * H + c];
    }
    atomicAdd(&pooled[curb * H + c], acc);
}

// ---- out = relu(pooled @ finW1 + finb1) @ finW2 + finb2 ----
__global__ void k_final(const float* __restrict__ pooled,
                        const float* __restrict__ W1, const float* __restrict__ b1,
                        const float* __restrict__ W2, const float* __restrict__ b2,
                        float* __restrict__ out) {
    __shared__ float h[H];
    int g = blockIdx.x;
    int j = threadIdx.x;
    const float* p = pooled + (size_t)g * H;
    float acc = b1[j];
    #pragma unroll 8
    for (int k = 0; k < H; ++k) acc += p[k] * W1[k * H + j];
    h[j] = fmaxf(acc, 0.f);
    __syncthreads();
    if (j < OUTC) {
        float o = b2[j];
        #pragma unroll 8
        for (int k = 0; k < H; ++k) o += h[k] * W2[k * OUTC + j];
        out[(size_t)g * OUTC + j] = o;
    }
}

extern "C" void kernel_launch(void* const* d_in, const int* in_sizes, int n_in,
                              void* d_out, int out_size, void* d_ws, size_t ws_size,
                              hipStream_t stream) {
    const float* x         = (const float*)d_in[0];
    const float* edge_attr = (const float*)d_in[1];
    const float* P[16];
    for (int i = 0; i < 16; ++i) P[i] = (const float*)d_in[2 + i];
    const float* finW1 = (const float*)d_in[18];
    const float* finb1 = (const float*)d_in[19];
    const float* finW2 = (const float*)d_in[20];
    const float* finb2 = (const float*)d_in[21];
    const int* row   = (const int*)d_in[22];
    const int* col   = row + E;
    const int* batch = (const int*)d_in[23];
    float* out = (float*)d_out;
    (void)ws_size; (void)n_in; (void)in_sizes; (void)out_size;

    // ---- workspace layout (floats first) ----
    float* fw = (float*)d_ws;
    float* xc1    = fw;  fw += (size_t)N * D;   // 4.8M floats
    float* xc2    = fw;  fw += (size_t)N * D;
    float* agg    = fw;  fw += (size_t)N * D;
    float* hrel   = fw;  fw += (size_t)N * H;
    float* hroot  = fw;  fw += (size_t)N * H;
    float* pooled = fw;  fw += (size_t)G * H;
    int* iw = (int*)fw;
    int* cntR   = iw;  iw += NB;      // cntR/cntC adjacent -> one memset
    int* cntC   = iw;  iw += NB;
    int* baseR  = iw;  iw += NB;
    int* baseC  = iw;  iw += NB;
    int* curR   = iw;  iw += NB;
    int* curC   = iw;  iw += NB;
    int* offR   = iw;  iw += N + 1;
    int* offC   = iw;  iw += N + 1;
    int* eid    = iw;  iw += E;
    int* srcrow = iw;  iw += E;
    // kv arrays alias agg/hrel/hroot (only live during build, before gprop)
    unsigned long long* kvR = (unsigned long long*)agg;
    unsigned long long* kvC = kvR + E;

    // ---- build CSR/CSC (two-level MSD binning) ----
    hipMemsetAsync(cntR, 0, 2 * (size_t)NB * sizeof(int), stream);
    hipMemsetAsync(pooled, 0, (size_t)G * H * sizeof(float), stream);
    int p1grid = (E + CHUNK - 1) / CHUNK;
    k_p1hist<<<p1grid, 256, 0, stream>>>(row, col, cntR, cntC);
    k_bscan<<<1, 256, 0, stream>>>(cntR, cntC, baseR, baseC, curR, curC, offR, offC);
    k_p1scat<<<p1grid, 256, 0, stream>>>(row, col, curR, curC, kvR, kvC);
    k_p2<<<2 * NB, 256, 0, stream>>>(kvR, kvC, baseR, baseC, cntR, cntC,
                                     offR, offC, eid, srcrow);

    // ---- edge_aggr into xc tails; x into xc1 head ----
    k_ea_gather<<<(N + 7) / 8, 256, 0, stream>>>(edge_attr, eid, offR, xc1, xc2);
    k_fill_x<<<(N * H + 255) / 256, 256, 0, stream>>>(x, xc1);

    // ---- layer 1 ----
    k_gprop<<<(N + 3) / 4, 256, 0, stream>>>(xc1, srcrow, offC, agg);
    k_mlp1<<<1024, 256, 0, stream>>>(agg, xc1, P[0], P[1], P[4], P[5], hrel, hroot);
    k_mlp2<<<1024, 256, 0, stream>>>(hrel, hroot, P[2], P[3], P[6], P[7], xc2, D);

    // ---- layer 2 ----
    k_gprop<<<(N + 3) / 4, 256, 0, stream>>>(xc2, srcrow, offC, agg);
    k_mlp1<<<1024, 256, 0, stream>>>(agg, xc2, P[8], P[9], P[12], P[13], hrel, hroot);
    k_mlp2<<<1024, 256, 0, stream>>>(hrel, hroot, P[10], P[11], P[14], P[15], agg, H);

    // ---- pool + head ----
    k_pool<<<(N / 16 + 3) / 4, 256, 0, stream>>>(agg, batch, pooled);
    k_final<<<G, 64, 0, stream>>>(pooled, finW1, finb1, finW2, finb2, out);
}

// Round 4
// 932.145 us; speedup vs baseline: 1.9344x; 1.0997x over previous
//
#include <hip/hip_runtime.h>

// NetEdge GNN, gather formulation, round 4: fix latency-bound gathers.
//   ea_gather/gprop now batch 8 edges per iteration into independent register
//   loads (8-16 gathers in flight per lane-group instead of 1-2).

namespace {
constexpr int N  = 50000;    // nodes
constexpr int E  = 1600000;  // edges
constexpr int G  = 256;      // graphs
constexpr int EC = 32;       // edge channels
constexpr int H  = 64;       // hidden / node channels
constexpr int D  = 96;       // concat dim (64 + 32)
constexpr int OUTC = 10;     // classes
constexpr int NB = (N + 255) / 256;   // 196 coarse buckets (node >> 8)
constexpr int CHUNK = 4096;           // edges per pass-1 block
}

// ---- pass 1a: coarse histograms (LDS-staged, 1 global atomic per bin/block) ----
__global__ __launch_bounds__(256) void k_p1hist(const int* __restrict__ row,
                                                const int* __restrict__ col,
                                                int* __restrict__ cntR,
                                                int* __restrict__ cntC) {
    __shared__ int hR[NB], hC[NB];
    for (int i = threadIdx.x; i < NB; i += 256) { hR[i] = 0; hC[i] = 0; }
    __syncthreads();
    int base = blockIdx.x * CHUNK;
    int end = min(base + CHUNK, E);
    for (int e = base + threadIdx.x; e < end; e += 256) {
        atomicAdd(&hR[row[e] >> 8], 1);
        atomicAdd(&hC[col[e] >> 8], 1);
    }
    __syncthreads();
    for (int i = threadIdx.x; i < NB; i += 256) {
        if (hR[i]) atomicAdd(&cntR[i], hR[i]);
        if (hC[i]) atomicAdd(&cntC[i], hC[i]);
    }
}

// ---- pass 1b: scan 196 bucket counts -> bases + cursors; off[N]=E ----
__global__ __launch_bounds__(256) void k_bscan(const int* __restrict__ cntR,
                                               const int* __restrict__ cntC,
                                               int* __restrict__ baseR, int* __restrict__ baseC,
                                               int* __restrict__ curR,  int* __restrict__ curC,
                                               int* __restrict__ offR,  int* __restrict__ offC) {
    __shared__ int sR[256], sC[256];
    int t = threadIdx.x;
    sR[t] = (t < NB) ? cntR[t] : 0;
    sC[t] = (t < NB) ? cntC[t] : 0;
    __syncthreads();
    for (int d = 1; d < 256; d <<= 1) {
        int vR = sR[t], vC = sC[t];
        int uR = (t >= d) ? sR[t - d] : 0;
        int uC = (t >= d) ? sC[t - d] : 0;
        __syncthreads();
        sR[t] = vR + uR; sC[t] = vC + uC;
        __syncthreads();
    }
    if (t < NB) {
        int bR = (t == 0) ? 0 : sR[t - 1];
        int bC = (t == 0) ? 0 : sC[t - 1];
        baseR[t] = bR; curR[t] = bR;
        baseC[t] = bC; curC[t] = bC;
    }
    if (t == 0) { offR[N] = E; offC[N] = E; }
}

// ---- pass 1c: coarse scatter of packed (key<<32|val), runs of ~21/bin ----
__global__ __launch_bounds__(256) void k_p1scat(const int* __restrict__ row,
                                                const int* __restrict__ col,
                                                int* __restrict__ curR, int* __restrict__ curC,
                                                unsigned long long* __restrict__ kvR,
                                                unsigned long long* __restrict__ kvC) {
    __shared__ int hR[NB], hC[NB];
    __shared__ int cR[NB], cC[NB];
    for (int i = threadIdx.x; i < NB; i += 256) { hR[i] = 0; hC[i] = 0; }
    __syncthreads();
    int base = blockIdx.x * CHUNK;
    int end = min(base + CHUNK, E);
    for (int e = base + threadIdx.x; e < end; e += 256) {
        atomicAdd(&hR[row[e] >> 8], 1);
        atomicAdd(&hC[col[e] >> 8], 1);
    }
    __syncthreads();
    for (int i = threadIdx.x; i < NB; i += 256) {
        cR[i] = hR[i] ? atomicAdd(&curR[i], hR[i]) : 0;
        cC[i] = hC[i] ? atomicAdd(&curC[i], hC[i]) : 0;
    }
    __syncthreads();
    for (int e = base + threadIdx.x; e < end; e += 256) {
        int r = row[e], c = col[e];
        int pR = atomicAdd(&cR[r >> 8], 1);
        kvR[pR] = ((unsigned long long)(unsigned)r << 32) | (unsigned)e;
        int pC = atomicAdd(&cC[c >> 8], 1);
        kvC[pC] = ((unsigned long long)(unsigned)c << 32) | (unsigned)r;
    }
}

// ---- pass 2: per-bucket fine bin; block b<NB handles CSR, else CSC ----
__global__ __launch_bounds__(256) void k_p2(const unsigned long long* __restrict__ kvR,
                                            const unsigned long long* __restrict__ kvC,
                                            const int* __restrict__ baseR, const int* __restrict__ baseC,
                                            const int* __restrict__ cntR,  const int* __restrict__ cntC,
                                            int* __restrict__ offR, int* __restrict__ offC,
                                            int* __restrict__ eid, int* __restrict__ srcrow) {
    bool isC = blockIdx.x >= NB;
    int b = isC ? blockIdx.x - NB : blockIdx.x;
    const unsigned long long* kv = isC ? kvC : kvR;
    int sbase = isC ? baseC[b] : baseR[b];
    int scnt  = isC ? cntC[b]  : cntR[b];
    int* off  = isC ? offC : offR;
    int* outv = isC ? srcrow : eid;

    __shared__ int hist[256], s[256], cur[256];
    int t = threadIdx.x;
    hist[t] = 0;
    __syncthreads();
    for (int i = sbase + t; i < sbase + scnt; i += 256) {
        atomicAdd(&hist[(int)(kv[i] >> 32) & 255], 1);
    }
    __syncthreads();
    s[t] = hist[t];
    __syncthreads();
    for (int d = 1; d < 256; d <<= 1) {
        int v = s[t];
        int u = (t >= d) ? s[t - d] : 0;
        __syncthreads();
        s[t] = v + u;
        __syncthreads();
    }
    int excl = (t == 0) ? 0 : s[t - 1];
    cur[t] = sbase + excl;
    int node = (b << 8) + t;
    if (node < N) off[node] = sbase + excl;
    __syncthreads();
    for (int i = sbase + t; i < sbase + scnt; i += 256) {
        unsigned long long p = kv[i];
        int lk = (int)(p >> 32) & 255;
        int pos = atomicAdd(&cur[lk], 1);
        outv[pos] = (int)(p & 0xffffffffu);
    }
}

// ---- edge_aggr gather, 8 edges in flight per 32-lane group ----
__global__ __launch_bounds__(256) void k_ea_gather(const float* __restrict__ edge_attr,
                                                   const int* __restrict__ eid,
                                                   const int* __restrict__ offR,
                                                   float* __restrict__ xc1,
                                                   float* __restrict__ xc2) {
    int n = blockIdx.x * 8 + (threadIdx.x >> 5);
    int c = threadIdx.x & 31;
    if (n >= N) return;
    int b = offR[n], e_end = offR[n + 1];
    float s = 0.f;
    for (int i0 = b; i0 < e_end; i0 += 8) {
        int cnt = min(8, e_end - i0);
        // lanes 0..7 (replicated 4x) fetch the next 8 edge ids
        int ev = eid[min(i0 + (c & 7), e_end - 1)];
        if (cnt == 8) {
            float v[8];
            #pragma unroll
            for (int j = 0; j < 8; ++j) {
                int e = __shfl(ev, j, 32);
                v[j] = edge_attr[(size_t)e * EC + c];
            }
            #pragma unroll
            for (int j = 0; j < 8; ++j) s += v[j];
        } else {
            for (int j = 0; j < cnt; ++j) {
                int e = __shfl(ev, j, 32);
                s += edge_attr[(size_t)e * EC + c];
            }
        }
    }
    xc1[(size_t)n * D + H + c] = s;
    xc2[(size_t)n * D + H + c] = s;
}

// ---- xc1[:, 0:64] = x ----
__global__ void k_fill_x(const float* __restrict__ x, float* __restrict__ xc1) {
    int tid = blockIdx.x * 256 + threadIdx.x;
    if (tid >= N * H) return;
    xc1[(size_t)(tid >> 6) * D + (tid & 63)] = x[tid];
}

// ---- agg[n] = sum over incoming edges of xc[src]; 8 edges in flight/wave ----
__global__ __launch_bounds__(256) void k_gprop(const float* __restrict__ xc,
                                               const int* __restrict__ srcrow,
                                               const int* __restrict__ offC,
                                               float* __restrict__ agg) {
    int n = blockIdx.x * 4 + (threadIdx.x >> 6);
    int lane = threadIdx.x & 63;
    if (n >= N) return;
    int b = offC[n], e_end = offC[n + 1];
    float a0 = 0.f, a1 = 0.f;
    for (int i0 = b; i0 < e_end; i0 += 8) {
        int cnt = min(8, e_end - i0);
        int rv = srcrow[min(i0 + (lane & 7), e_end - 1)];
        const float* s[8];
        #pragma unroll
        for (int j = 0; j < 8; ++j) {
            int rj = __shfl(rv, j);
            s[j] = xc + (size_t)rj * D;
        }
        if (cnt == 8) {
            float v[8], w[8];
            #pragma unroll
            for (int j = 0; j < 8; ++j) v[j] = s[j][lane];
            #pragma unroll
            for (int j = 0; j < 8; ++j) w[j] = (lane < 32) ? s[j][H + lane] : 0.f;
            #pragma unroll
            for (int j = 0; j < 8; ++j) { a0 += v[j]; a1 += w[j]; }
        } else {
            for (int j = 0; j < cnt; ++j) {
                a0 += s[j][lane];
                if (lane < 32) a1 += s[j][H + lane];
            }
        }
    }
    agg[(size_t)n * D + lane] = a0;
    if (lane < 32) agg[(size_t)n * D + H + lane] = a1;
}

// ---- h_rel = relu(agg @ relW1 + b); h_root = relu(xc @ rootW1 + b) ----
__global__ __launch_bounds__(256) void k_mlp1(const float* __restrict__ agg,
                       const float* __restrict__ xc,
                       const float* __restrict__ relW1, const float* __restrict__ relb1,
                       const float* __restrict__ rootW1, const float* __restrict__ rootb1,
                       float* __restrict__ hrel, float* __restrict__ hroot) {
    __shared__ float sWr[D * H];
    __shared__ float sWo[D * H];
    for (int i = threadIdx.x; i < D * H; i += 256) {
        sWr[i] = relW1[i];
        sWo[i] = rootW1[i];
    }
    __syncthreads();
    int lane = threadIdx.x & 63;
    int wid  = threadIdx.x >> 6;
    int nwaves = gridDim.x * 4;
    float br = relb1[lane];
    float bo = rootb1[lane];
    for (int n = blockIdx.x * 4 + wid; n < N; n += nwaves) {
        const float* a  = agg + (size_t)n * D;
        const float* xr = xc  + (size_t)n * D;
        float accr = br, acco = bo;
        #pragma unroll 8
        for (int k = 0; k < D; ++k) {
            accr += a[k]  * sWr[k * H + lane];
            acco += xr[k] * sWo[k * H + lane];
        }
        hrel[(size_t)n * H + lane]  = fmaxf(accr, 0.f);
        hroot[(size_t)n * H + lane] = fmaxf(acco, 0.f);
    }
}

// ---- x_out = relu(hrel @ relW2 + hroot @ rootW2 + b), strided output ----
__global__ __launch_bounds__(256) void k_mlp2(const float* __restrict__ hrel,
                       const float* __restrict__ hroot,
                       const float* __restrict__ relW2, const float* __restrict__ relb2,
                       const float* __restrict__ rootW2, const float* __restrict__ rootb2,
                       float* __restrict__ xout, int ostride) {
    __shared__ float sWr[H * H];
    __shared__ float sWo[H * H];
    for (int i = threadIdx.x; i < H * H; i += 256) {
        sWr[i] = relW2[i];
        sWo[i] = rootW2[i];
    }
    __syncthreads();
    int lane = threadIdx.x & 63;
    int wid  = threadIdx.x >> 6;
    int nwaves = gridDim.x * 4;
    float b = relb2[lane] + rootb2[lane];
    for (int n = blockIdx.x * 4 + wid; n < N; n += nwaves) {
        const float* hr = hrel  + (size_t)n * H;
        const float* ho = hroot + (size_t)n * H;
        float acc = b;
        #pragma unroll 8
        for (int k = 0; k < H; ++k) {
            acc += hr[k] * sWr[k * H + lane] + ho[k] * sWo[k * H + lane];
        }
        xout[(size_t)n * ostride + lane] = fmaxf(acc, 0.f);
    }
}

// ---- pooled[batch[n]] += x[n], 16-node register pre-reduce (batch sorted) ----
__global__ __launch_bounds__(256) void k_pool(const float* __restrict__ x,
                                              const int* __restrict__ batch,
                                              float* __restrict__ pooled) {
    int c = threadIdx.x & 63;
    int grp = blockIdx.x * 4 + (threadIdx.x >> 6);
    int n0 = grp * 16;
    if (n0 >= N) return;
    int nend = min(n0 + 16, N);
    int curb = batch[n0];
    float acc = 0.f;
    for (int n = n0; n < nend; ++n) {
        int b = batch[n];
        if (b != curb) {
            atomicAdd(&pooled[curb * H + c], acc);
            acc = 0.f;
            curb = b;
        }
        acc += x[(size_t)n * H + c];
    }
    atomicAdd(&pooled[curb * H + c], acc);
}

// ---- out = relu(pooled @ finW1 + finb1) @ finW2 + finb2 ----
__global__ void k_final(const float* __restrict__ pooled,
                        const float* __restrict__ W1, const float* __restrict__ b1,
                        const float* __restrict__ W2, const float* __restrict__ b2,
                        float* __restrict__ out) {
    __shared__ float h[H];
    int g = blockIdx.x;
    int j = threadIdx.x;
    const float* p = pooled + (size_t)g * H;
    float acc = b1[j];
    #pragma unroll 8
    for (int k = 0; k < H; ++k) acc += p[k] * W1[k * H + j];
    h[j] = fmaxf(acc, 0.f);
    __syncthreads();
    if (j < OUTC) {
        float o = b2[j];
        #pragma unroll 8
        for (int k = 0; k < H; ++k) o += h[k] * W2[k * OUTC + j];
        out[(size_t)g * OUTC + j] = o;
    }
}

extern "C" void kernel_launch(void* const* d_in, const int* in_sizes, int n_in,
                              void* d_out, int out_size, void* d_ws, size_t ws_size,
                              hipStream_t stream) {
    const float* x         = (const float*)d_in[0];
    const float* edge_attr = (const float*)d_in[1];
    const float* P[16];
    for (int i = 0; i < 16; ++i) P[i] = (const float*)d_in[2 + i];
    const float* finW1 = (const float*)d_in[18];
    const float* finb1 = (const float*)d_in[19];
    const float* finW2 = (const float*)d_in[20];
    const float* finb2 = (const float*)d_in[21];
    const int* row   = (const int*)d_in[22];
    const int* col   = row + E;
    const int* batch = (const int*)d_in[23];
    float* out = (float*)d_out;
    (void)ws_size; (void)n_in; (void)in_sizes; (void)out_size;

    // ---- workspace layout (floats first) ----
    float* fw = (float*)d_ws;
    float* xc1    = fw;  fw += (size_t)N * D;
    float* xc2    = fw;  fw += (size_t)N * D;
    float* agg    = fw;  fw += (size_t)N * D;
    float* hrel   = fw;  fw += (size_t)N * H;
    float* hroot  = fw;  fw += (size_t)N * H;
    float* pooled = fw;  fw += (size_t)G * H;
    int* iw = (int*)fw;
    int* cntR   = iw;  iw += NB;
    int* cntC   = iw;  iw += NB;
    int* baseR  = iw;  iw += NB;
    int* baseC  = iw;  iw += NB;
    int* curR   = iw;  iw += NB;
    int* curC   = iw;  iw += NB;
    int* offR   = iw;  iw += N + 1;
    int* offC   = iw;  iw += N + 1;
    int* eid    = iw;  iw += E;
    int* srcrow = iw;  iw += E;
    // kv arrays alias agg/hrel (only live during build, before gprop)
    unsigned long long* kvR = (unsigned long long*)agg;
    unsigned long long* kvC = kvR + E;

    // ---- build CSR/CSC (two-level MSD binning) ----
    hipMemsetAsync(cntR, 0, 2 * (size_t)NB * sizeof(int), stream);
    hipMemsetAsync(pooled, 0, (size_t)G * H * sizeof(float), stream);
    int p1grid = (E + CHUNK - 1) / CHUNK;
    k_p1hist<<<p1grid, 256, 0, stream>>>(row, col, cntR, cntC);
    k_bscan<<<1, 256, 0, stream>>>(cntR, cntC, baseR, baseC, curR, curC, offR, offC);
    k_p1scat<<<p1grid, 256, 0, stream>>>(row, col, curR, curC, kvR, kvC);
    k_p2<<<2 * NB, 256, 0, stream>>>(kvR, kvC, baseR, baseC, cntR, cntC,
                                     offR, offC, eid, srcrow);

    // ---- edge_aggr into xc tails; x into xc1 head ----
    k_ea_gather<<<(N + 7) / 8, 256, 0, stream>>>(edge_attr, eid, offR, xc1, xc2);
    k_fill_x<<<(N * H + 255) / 256, 256, 0, stream>>>(x, xc1);

    // ---- layer 1 ----
    k_gprop<<<(N + 3) / 4, 256, 0, stream>>>(xc1, srcrow, offC, agg);
    k_mlp1<<<1024, 256, 0, stream>>>(agg, xc1, P[0], P[1], P[4], P[5], hrel, hroot);
    k_mlp2<<<1024, 256, 0, stream>>>(hrel, hroot, P[2], P[3], P[6], P[7], xc2, D);

    // ---- layer 2 ----
    k_gprop<<<(N + 3) / 4, 256, 0, stream>>>(xc2, srcrow, offC, agg);
    k_mlp1<<<1024, 256, 0, stream>>>(agg, xc2, P[8], P[9], P[12], P[13], hrel, hroot);
    k_mlp2<<<1024, 256, 0, stream>>>(hrel, hroot, P[10], P[11], P[14], P[15], agg, H);

    // ---- pool + head ----
    k_pool<<<(N / 16 + 3) / 4, 256, 0, stream>>>(agg, batch, pooled);
    k_final<<<G, 64, 0, stream>>>(pooled, finW1, finb1, finW2, finb2, out);
}